// Round 13
// baseline (52.801 us; speedup 1.0000x reference)
//
#include <hip/hip_runtime.h>
#include <hip/hip_bf16.h>

#define H_IN 4096
#define W_IN 4096
#define KH 15
#define KW 15
#define OH (H_IN - KH + 1)   // 4082
#define OW (W_IN - KW + 1)   // 4082

#define BM 64                // output rows per block (4 waves x 16)
#define BN 128               // output cols per block (NJ=8 j-frags)
#define NJ (BN / 16)         // 8
#define SROWS (BM + KH - 1)  // 78 staged rows
#define SGROW 18             // staged 16B granules per row (144 bf16 cols)
#define SSTR  192            // row stride in ushort = 24 granules = 384 B (3x128B):
                             // row base granule = 24r = 0 mod 8, so granule
                             // swizzle g^(r&7) is an in-row involution (rule #21)
#define STAGE_N (SROWS * SGROW)  // 1404 16B items
#define NIT 6                // ceil(STAGE_N / 256) items per thread

typedef __attribute__((ext_vector_type(8))) short short8;   // MFMA A/B frag
typedef __attribute__((ext_vector_type(4))) float f32x4;    // MFMA C/D frag

__device__ __forceinline__ ushort f2bf(float f) {
    __hip_bfloat16 h = __float2bfloat16(f);       // native v_cvt path
    return __builtin_bit_cast(ushort, h);
}

// ---- prep: build banded Toeplitz weight frags into workspace (15 KB) ----
// B[k][j] = w[kh][k-j]; frag layout: lane l holds B[8*(l>>4)+u][l&15], u=0..7
__global__ __launch_bounds__(256)
void build_wfrags(const float* __restrict__ Wt, ushort* __restrict__ Bw)
{
    int idx = blockIdx.x * 256 + threadIdx.x;
    if (idx < KH * 64) {
        int kh = idx >> 6, l = idx & 63;
        int j = l & 15, k0 = (l >> 4) * 8;
        union { ushort u[8]; uint4 v; } t;
#pragma unroll
        for (int u = 0; u < 8; ++u) {
            int kw = k0 + u - j;
            t.u[u] = f2bf((kw >= 0 && kw < KW) ? Wt[kh * KW + kw] : 0.0f);
        }
        *reinterpret_cast<uint4*>(&Bw[idx * 8]) = t.v;
    }
}

__global__ __launch_bounds__(256, 4)
void conv2d_mfma_bf16(const float* __restrict__ X,
                      const ushort* __restrict__ Bw,
                      const float* __restrict__ Bias,
                      float* __restrict__ Out)
{
    __shared__ ushort s_x[SROWS * SSTR];     // 29952 B

    const int tid = threadIdx.x;
    const int l = tid & 63;
    const int w = tid >> 6;
    const int ox0 = blockIdx.x * BN;
    const int oy0 = blockIdx.y * BM;
    const bool xint = (ox0 + SGROW * 8 <= W_IN);

    // ---- stage phase A: issue ALL tile loads (T14 split, one vmcnt drain) ----
    float4 v[2 * NIT];
#pragma unroll
    for (int k = 0; k < NIT; ++k) {
        int i = tid + 256 * k;
        if (i < STAGE_N) {
            int r = i / SGROW;
            int g = i % SGROW;
            int gy = min(oy0 + r, H_IN - 1);
            const float* rp = X + (size_t)gy * W_IN;
            int gx = ox0 + g * 8;
            if (xint) {
                v[2 * k + 0] = *reinterpret_cast<const float4*>(rp + gx);
                v[2 * k + 1] = *reinterpret_cast<const float4*>(rp + gx + 4);
            } else {
                v[2 * k + 0].x = rp[min(gx + 0, W_IN - 1)];
                v[2 * k + 0].y = rp[min(gx + 1, W_IN - 1)];
                v[2 * k + 0].z = rp[min(gx + 2, W_IN - 1)];
                v[2 * k + 0].w = rp[min(gx + 3, W_IN - 1)];
                v[2 * k + 1].x = rp[min(gx + 4, W_IN - 1)];
                v[2 * k + 1].y = rp[min(gx + 5, W_IN - 1)];
                v[2 * k + 1].z = rp[min(gx + 6, W_IN - 1)];
                v[2 * k + 1].w = rp[min(gx + 7, W_IN - 1)];
            }
        }
    }
    // ---- stage phase B: convert + swizzled 16B LDS writes ----
#pragma unroll
    for (int k = 0; k < NIT; ++k) {
        int i = tid + 256 * k;
        if (i < STAGE_N) {
            int r = i / SGROW;
            int g = i % SGROW;
            uint4 pk;
            pk.x = (uint32_t)f2bf(v[2 * k + 0].x) | ((uint32_t)f2bf(v[2 * k + 0].y) << 16);
            pk.y = (uint32_t)f2bf(v[2 * k + 0].z) | ((uint32_t)f2bf(v[2 * k + 0].w) << 16);
            pk.z = (uint32_t)f2bf(v[2 * k + 1].x) | ((uint32_t)f2bf(v[2 * k + 1].y) << 16);
            pk.w = (uint32_t)f2bf(v[2 * k + 1].z) | ((uint32_t)f2bf(v[2 * k + 1].w) << 16);
            *reinterpret_cast<uint4*>(&s_x[r * SSTR + ((g ^ (r & 7)) << 3)]) = pk;
        }
    }
    __syncthreads();       // only barrier in the kernel

    // ---- B-frags: L1-hot global loads (compiler chooses per-kh placement) ----
    const ushort* const bbase = Bw + l * 8;
    short8 bfr[KH];
#pragma unroll
    for (int kh = 0; kh < KH; ++kh)
        bfr[kh] = *reinterpret_cast<const short8*>(bbase + kh * 64 * 8);
    __builtin_amdgcn_sched_barrier(0);

    // ---- compute: per kh {8 swizzled A-reads, 8 MFMAs} ----
    const int r0  = w * 16 + (l & 15);   // A row base (local)
    const int gc0 = l >> 4;              // A col granule base

    f32x4 acc[NJ];
#pragma unroll
    for (int j = 0; j < NJ; ++j) acc[j] = (f32x4){0.f, 0.f, 0.f, 0.f};

#pragma unroll
    for (int kh = 0; kh < KH; ++kh) {
        const int rr = r0 + kh;
        const int rowb = rr * SSTR;
        const int x7 = rr & 7;
#pragma unroll
        for (int j = 0; j < NJ; ++j) {
            int off = rowb + (((gc0 + 2 * j) ^ x7) << 3);
            short8 a = *reinterpret_cast<const short8*>(&s_x[off]);
            acc[j] = __builtin_amdgcn_mfma_f32_16x16x32_bf16(a, bfr[kh], acc[j], 0, 0, 0);
        }
    }

    // ---- store: C/D layout col=lane&15, row=(lane>>4)*4+r ----
    const float b = Bias[0];
    const int orow0 = oy0 + w * 16 + (l >> 4) * 4;
    const int ocol  = ox0 + (l & 15);
    if (oy0 + BM <= OH && ox0 + BN <= OW) {
        float* op0 = &Out[(size_t)orow0 * OW + ocol];
#pragma unroll
        for (int j = 0; j < NJ; ++j) {
#pragma unroll
            for (int r = 0; r < 4; ++r)
                op0[(size_t)r * OW + j * 16] = acc[j][r] + b;
        }
    } else {
#pragma unroll
        for (int j = 0; j < NJ; ++j) {
            int oc = ocol + j * 16;
            if (oc < OW) {
#pragma unroll
                for (int r = 0; r < 4; ++r) {
                    int orow = orow0 + r;
                    if (orow < OH)
                        Out[(size_t)orow * OW + oc] = acc[j][r] + b;
                }
            }
        }
    }
}

extern "C" void kernel_launch(void* const* d_in, const int* in_sizes, int n_in,
                              void* d_out, int out_size, void* d_ws, size_t ws_size,
                              hipStream_t stream)
{
    const float* X    = (const float*)d_in[0];
    const float* Wt   = (const float*)d_in[1];
    const float* Bias = (const float*)d_in[2];
    float* Out        = (float*)d_out;
    ushort* Bw        = (ushort*)d_ws;        // 15*64*8 ushort = 15360 B

    hipLaunchKernelGGL(build_wfrags, dim3((KH * 64 + 255) / 256), dim3(256), 0, stream,
                       Wt, Bw);

    dim3 grid((OW + BN - 1) / BN,    // 32
              (OH + BM - 1) / BM);   // 64
    dim3 block(256);
    hipLaunchKernelGGL(conv2d_mfma_bf16, grid, block, 0, stream, X, Bw, Bias, Out);
}